// Round 10
// baseline (114.209 us; speedup 1.0000x reference)
//
#include <hip/hip_runtime.h>
#include <stdint.h>

#define HH 224
#define WW 224
#define BB 4
#define PP 7          // seams per direction
#define SEG 28
#define BW 5
#define MM 11         // 2*BW+1

#define POS_INF_I 0x7F800000

typedef const __attribute__((address_space(1))) unsigned int* gas_ptr;
typedef __attribute__((address_space(3))) unsigned int* las_ptr;
typedef unsigned long long ull;

__device__ __forceinline__ int iclamp(int v, int lo, int hi) {
    return min(max(v, lo), hi);
}

// map-compose for 11-entry 4-bit-nibble maps packed in u64:  H[i] = F[G[i]]
__device__ inline ull mcompose(ull F, ull G) {
    ull H = 0ull;
#pragma unroll
    for (int i = 0; i < 11; ++i) {
        unsigned g = (unsigned)(G >> (4 * i)) & 15u;
        H |= ((F >> (4 * g)) & 15ull) << (4 * i);
    }
    return H;
}

// ---------------------------------------------------------------------------
// XCD-consistent tile map (R6-proven; R8-verified decode).
// 784 blocks -> 16x16 tiles (14x14x4). v = (p&7)*98 + p>>3 (bijective).
// ---------------------------------------------------------------------------
__device__ __forceinline__ void tile_map(int& bx, int& by, int& b) {
    int p = blockIdx.x;
    int v = (p & 7) * 98 + (p >> 3);
    bx = v % 14;
    int r = v / 14;         // r = b*14 + by, range 0..55
    by = r % 14;
    b  = r / 14;
}

// square 8x8 wave quadrants inside the 16x16 tile (R8-verified)
__device__ __forceinline__ void lane_map(int t, int& tx, int& ty) {
    const int lane = t & 63;
    const int w    = t >> 6;
    tx = ((w & 1) << 3) + (lane & 7);
    ty = ((w >> 1) << 3) + (lane >> 3);
}

// ---------------------------------------------------------------------------
// DP kernel (verified absmax 0 — unchanged)
// ---------------------------------------------------------------------------
__global__ __launch_bounds__(64) void dp_kernel(const float* __restrict__ grad,
                                                int* __restrict__ coords_v,
                                                int* __restrict__ coords_h) {
    __shared__ __align__(16) float gseg[225 * 16];

    const int tid = threadIdx.x;
    const int l   = tid & 15;
    const int sid = blockIdx.x;
    const int p   = sid % PP;
    const int dir = (sid / PP) & 1;
    const int b   = sid / (2 * PP);
    const int base = SEG * (p + 1);
    const float* gb = grad + b * (HH * WW);

    {
        const int r  = tid >> 4;
        const int m  = tid & 15;
        const int sS = (dir == 0) ? WW : 1;
        const int sM = (dir == 0) ? 1  : WW;
        const float* src = gb + r * sS + (base - BW + m) * sM;
        const long stepBytes = (long)(4 * sS) * 4;
#pragma unroll 8
        for (int c = 0; c < 56; ++c) {
            __builtin_amdgcn_global_load_lds((gas_ptr)(const void*)src,
                                             (las_ptr)(void*)(&gseg[c * 64]), 4, 0, 0);
            src = (const float*)((const char*)src + stepBytes);
        }
    }
    __syncthreads();

    const float lane_add = (l < MM) ? 0.0f : __int_as_float(POS_INF_I);
    const float* gp = &gseg[l];

    unsigned wreg[16] = {};

#define DP_STEP(gval, ownb, jj_c)                                                       \
    {                                                                                   \
        float v1 = cost;                                                                \
        float v0 = __int_as_float(__builtin_amdgcn_update_dpp(                          \
            POS_INF_I, __float_as_int(cost), 0x111, 0xf, 0xf, false));                  \
        float v2 = __int_as_float(__builtin_amdgcn_update_dpp(                          \
            POS_INF_I, __float_as_int(cost), 0x101, 0xf, 0xf, false));                  \
        bool a01 = (v0 <= v1), a02 = (v0 <= v2), a12 = (v1 <= v2);                      \
        bool aa  = a01 && a02;                                                          \
        unsigned long long A   = __ballot(aa);                                          \
        unsigned long long C12 = __ballot(a12);                                         \
        unsigned long long B0 = ~A & C12;                                               \
        unsigned long long B1 = ~A & ~C12;                                              \
        float mv = aa ? v0 : (a12 ? v1 : v2);                                           \
        cost = mv - (gval) + lane_add;                                                  \
        unsigned wv = (unsigned)(B0 & 0x7FFull) | ((unsigned)(B1 & 0x7FFull) << 11);    \
        wreg[(jj_c)] = (ownb) ? wv : wreg[(jj_c)];                                      \
    }

    float cost = -gp[0] + lane_add;
    float buf[16], c0[16];
#pragma unroll
    for (int k = 0; k < 16; ++k) buf[k] = gp[(1 + k) * 16];
    for (int t = 0; t < 13; ++t) {
        const bool own = (tid == t);
#pragma unroll
        for (int k = 0; k < 16; ++k) c0[k] = buf[k];
#pragma unroll
        for (int k = 0; k < 16; ++k) buf[k] = gp[(16 * (t + 1) + 1 + k) * 16];
#pragma unroll
        for (int k = 0; k < 16; ++k) DP_STEP(c0[k], own, k)
    }
    {
        const bool own = (tid == 13);
#pragma unroll
        for (int k = 0; k < 15; ++k) DP_STEP(buf[k], own, k)
    }
#undef DP_STEP

    float bc = cost;
    int   bi = l;
#pragma unroll
    for (int mask = 1; mask < 16; mask <<= 1) {
        float oc = __shfl_xor(bc, mask, 16);
        int   oi = __shfl_xor(bi, mask, 16);
        if (oc < bc || (oc == bc && oi < bi)) { bc = oc; bi = oi; }
    }
    const int idx_last = bi;

    const int mcnt = (l < 13) ? 16 : ((l == 13) ? 15 : 0);
    const ull IDMAP = 0xA9876543210ull;
    ull L = IDMAP;
#pragma unroll
    for (int jj = 15; jj >= 0; --jj) {
        if (jj < mcnt) {
            unsigned ww = wreg[jj];
            ull M = 0ull;
#pragma unroll
            for (int i = 0; i < MM; ++i) {
                unsigned sel = ((ww >> i) & 1u) + 2u * ((ww >> (11 + i)) & 1u);
                M |= ((ull)(i + (int)sel - 1)) << (4 * i);
            }
            L = mcompose(M, L);
        }
    }
    ull I = L;
#pragma unroll
    for (int d = 1; d < 16; d <<= 1) {
        ull O = __shfl_down(I, d, 16);
        if (l + d < 16) I = mcompose(I, O);
    }
    ull R = __shfl_down(I, 1, 16);
    if (l == 15) R = IDMAP;

    int* cout = (dir == 0) ? coords_v : coords_h;
    if (tid == 15) cout[(b * HH + 223) * PP + p] = base + idx_last - BW;
    if (tid < 16) {
        unsigned v = (unsigned)(R >> (4 * idx_last)) & 15u;
#pragma unroll
        for (int jj = 15; jj >= 0; --jj) {
            if (jj < mcnt) {
                unsigned ww = wreg[jj];
                unsigned sel = ((ww >> v) & 1u) + 2u * ((ww >> (11 + v)) & 1u);
                v = v + sel - 1u;
                cout[(b * HH + (16 * l + jj)) * PP + p] = base + (int)v - BW;
            }
        }
    }
}

// ---------------------------------------------------------------------------
// Proven LDS-bins slow path (round-0 logic, verbatim). (x,y) = the voting
// pixel's true (clamped) global coords; guards give exact zero-padding.
// ---------------------------------------------------------------------------
__device__ __forceinline__ int slow_vote_bins(const ull* rows, int x, int y, int t,
                                              unsigned* __restrict__ bins) {
#pragma unroll
    for (int c = 0; c < 16; ++c) bins[c * 256 + t] = 0u;
#pragma unroll
    for (int dy = -3; dy <= 3; ++dy) {
        if ((unsigned)(y + dy) >= (unsigned)HH) continue;
        ull row = rows[dy + 3];
        const int ay = dy < 0 ? -dy : dy;
#pragma unroll
        for (int dx = -3; dx <= 3; ++dx) {
            if ((unsigned)(x + dx) >= (unsigned)WW) continue;
            int lb = (int)((row >> (8 * (dx + 3))) & 255u);
            const int ax = dx < 0 ? -dx : dx;
            const int d = ay > ax ? ay : ax;
            const unsigned wgt = (d <= 1) ? 3u : (unsigned)(4 - d);
            atomicAdd(&bins[(lb >> 2) * 256 + t], wgt << ((lb & 3) * 8));
        }
    }
    int best_s = 0, best_k = 0;
#pragma unroll
    for (int c = 0; c < 16; ++c) {
        unsigned wd = bins[c * 256 + t];
        if (wd) {
#pragma unroll
            for (int q = 0; q < 4; ++q) {
                int s = (int)((wd >> (q * 8)) & 255u);
                if (s > best_s) { best_s = s; best_k = c * 4 + q; }
            }
        }
    }
    return best_k;
}

// ---------------------------------------------------------------------------
// 7x7 window gather from an LDS label region (stride STR). R5-verified.
// ---------------------------------------------------------------------------
template<int STR>
__device__ __forceinline__ void gather7(const unsigned char* lab,
                                        int cx0, int cy0, ull* rows) {
#pragma unroll
    for (int r = 0; r < 7; ++r) {
        int o  = (cy0 + r) * STR + cx0;
        int a8 = o & ~7;
        int sh = (o & 7) * 8;
        ull lo = *reinterpret_cast<const ull*>(lab + a8);
        ull hi = *reinterpret_cast<const ull*>(lab + a8 + 8);
        ull row = lo >> sh;
        if (sh) row |= hi << (64 - sh);
        rows[r] = row & 0x00FFFFFFFFFFFFFFull;
    }
}

// uniform fast path (exact) else proven bins path
__device__ __forceinline__ int do_vote(const ull* rows, int x, int y, int t,
                                       unsigned* __restrict__ bins) {
    const unsigned cl = (unsigned)((rows[3] >> 24) & 255u);
    const ull rep = (ull)cl * 0x0001010101010101ull;
    bool uni = true;
#pragma unroll
    for (int k = 0; k < 7; ++k) uni = uni && (rows[k] == rep);
    if (uni) return (int)cl;
    return slow_vote_bins(rows, x, y, t, bins);
}

// ---------------------------------------------------------------------------
// K_A: analytic labels (clamped 28x28) -> v1 (22x22) -> v2 (16x16 tile).
// Clamped-region semantics (R4/R5-verified). LDS 19376 B. Grid 784 x 256.
// ---------------------------------------------------------------------------
__global__ __launch_bounds__(256) void labvote12_kernel(const int* __restrict__ cv,
                                                        const int* __restrict__ ch,
                                                        unsigned char* __restrict__ out8) {
    __shared__ int cvs[28 * PP];                           // rows GY0-6.. (clamped)
    __shared__ int chs[28 * PP];                           // cols GX0-6.. (clamped)
    __shared__ __align__(8) unsigned char labL[28 * 32];   // labels, 28x28
    __shared__ __align__(8) unsigned char labM[22 * 24];   // v1 out, 22x22
    __shared__ unsigned bins[16 * 256];

    const int t = threadIdx.x;
    int tx, ty;  lane_map(t, tx, ty);
    int bxt, byt, b;  tile_map(bxt, byt, b);
    const int GX0 = bxt * 16, GY0 = byt * 16;

    for (int idx = t; idx < 28 * PP; idx += 256) {
        int gyc = iclamp(GY0 - 6 + idx / PP, 0, HH - 1);
        cvs[idx] = cv[(b * HH + gyc) * PP + idx % PP];
    }
    for (int idx = t; idx < 28 * PP; idx += 256) {
        int gxc = iclamp(GX0 - 6 + idx / PP, 0, WW - 1);
        chs[idx] = ch[(b * WW + gxc) * PP + idx % PP];
    }
    __syncthreads();

    // analytic labels over clamped 28x28
    for (int idx = t; idx < 28 * 28; idx += 256) {
        int j = idx / 28, i = idx - j * 28;
        int gxc = iclamp(GX0 - 6 + i, 0, WW - 1);
        int gyc = iclamp(GY0 - 6 + j, 0, HH - 1);
        int v = 0, h = 0;
#pragma unroll
        for (int q = 0; q < PP; ++q) {
            v += (cvs[j * PP + q] <= gxc);
            h += (chs[i * PP + q] <= gyc);
        }
        labL[j * 32 + i] = (unsigned char)(v + 8 * h);
    }
    __syncthreads();

    // v1 over 22x22 (voting pixel = clamp(GX0-3+i, GY0-3+j))
    for (int idx = t; idx < 22 * 22; idx += 256) {
        int j = idx / 22, i = idx - j * 22;
        int gxc = iclamp(GX0 - 3 + i, 0, WW - 1);
        int gyc = iclamp(GY0 - 3 + j, 0, HH - 1);
        int cx0 = gxc - GX0 + 3;            // window origin in labL (origin -6)
        int cy0 = gyc - GY0 + 3;
        ull rows[7];
        gather7<32>(labL, cx0, cy0, rows);
        labM[j * 24 + i] = (unsigned char)do_vote(rows, gxc, gyc, t, bins);
    }
    __syncthreads();

    // v2 for the 16x16 tile (square quadrants)
    {
        const int x = GX0 + tx, y = GY0 + ty;
        ull rows[7];
        gather7<24>(labM, tx, ty, rows);
        out8[(b * HH + y) * WW + x] = (unsigned char)do_vote(rows, x, y, t, bins);
    }
}

// ---------------------------------------------------------------------------
// K_B: stage v2 image (clamped 28x28) -> v3 (22x22) -> v4 (16x16).
// LDS 17808 B. Grid 784 x 256.
// ---------------------------------------------------------------------------
__global__ __launch_bounds__(256) void vote34_kernel(const unsigned char* __restrict__ in,
                                                     unsigned char* __restrict__ out8) {
    __shared__ __align__(8) unsigned char labL[28 * 32];   // staged v2, 28x28
    __shared__ __align__(8) unsigned char labM[22 * 24];   // v3 out, 22x22
    __shared__ unsigned bins[16 * 256];

    const int t = threadIdx.x;
    int tx, ty;  lane_map(t, tx, ty);
    int bxt, byt, b;  tile_map(bxt, byt, b);
    const int GX0 = bxt * 16, GY0 = byt * 16;
    const unsigned char* img = in + b * (HH * WW);

    for (int idx = t; idx < 28 * 28; idx += 256) {
        int j = idx / 28, i = idx - j * 28;
        int gxc = iclamp(GX0 - 6 + i, 0, WW - 1);
        int gyc = iclamp(GY0 - 6 + j, 0, HH - 1);
        labL[j * 32 + i] = img[gyc * WW + gxc];
    }
    __syncthreads();

    // v3 over 22x22
    for (int idx = t; idx < 22 * 22; idx += 256) {
        int j = idx / 22, i = idx - j * 22;
        int gxc = iclamp(GX0 - 3 + i, 0, WW - 1);
        int gyc = iclamp(GY0 - 3 + j, 0, HH - 1);
        int cx0 = gxc - GX0 + 3;
        int cy0 = gyc - GY0 + 3;
        ull rows[7];
        gather7<32>(labL, cx0, cy0, rows);
        labM[j * 24 + i] = (unsigned char)do_vote(rows, gxc, gyc, t, bins);
    }
    __syncthreads();

    // v4 for the 16x16 tile
    {
        const int x = GX0 + tx, y = GY0 + ty;
        ull rows[7];
        gather7<24>(labM, tx, ty, rows);
        out8[(b * HH + y) * WW + x] = (unsigned char)do_vote(rows, x, y, t, bins);
    }
}

// ---------------------------------------------------------------------------
// K_C: v5 — R8-verified vote body (global dword gather, uniform fast path,
// bins slow path), int32 output. READS ws, WRITES d_out (disjoint — the
// R0/R8 aliasing invariant). Grid 784 x 256.
// ---------------------------------------------------------------------------
__global__ __launch_bounds__(256) void vote_kernel(const unsigned char* __restrict__ in,
                                                   int* __restrict__ out32) {
    __shared__ unsigned bins[16 * 256];
    const int t = threadIdx.x;
    int tx, ty;  lane_map(t, tx, ty);
    int bxt, byt, b;  tile_map(bxt, byt, b);
    const int x = bxt * 16 + tx;
    const int y = byt * 16 + ty;
    const unsigned char* img = in + b * (HH * WW);

    ull rows[7];
    const bool xedge = (bxt == 0) || (bxt == 13);
    if (!xedge) {
        const unsigned* img32 = (const unsigned*)img;
        const int o0 = x - 3;
#pragma unroll
        for (int dy = -3; dy <= 3; ++dy) {
            int yc = min(max(y + dy, 0), HH - 1);
            int o  = yc * WW + o0;
            int a  = o >> 2;
            int sh = (o & 3) * 8;
            unsigned d0 = img32[a], d1 = img32[a + 1], d2 = img32[a + 2];
            ull lo = ((ull)d1 << 32) | d0;
            ull row = lo >> sh;
            if (sh) row |= (ull)d2 << (64 - sh);
            rows[dy + 3] = row & 0x00FFFFFFFFFFFFFFull;
        }
    } else {
#pragma unroll
        for (int dy = -3; dy <= 3; ++dy) {
            int yc = min(max(y + dy, 0), HH - 1);
            ull row = 0ull;
#pragma unroll
            for (int dx = -3; dx <= 3; ++dx) {
                int xc = min(max(x + dx, 0), WW - 1);
                row |= (ull)img[yc * WW + xc] << (8 * (dx + 3));
            }
            rows[dy + 3] = row;
        }
    }

    out32[(b * HH + y) * WW + x] = do_vote(rows, x, y, t, bins);
}

// ---------------------------------------------------------------------------
// Buffer plan (race-free; the R0/R8 invariant):
//   K_A: writes laD = d_out   (uint8 intermediate; d_out is write-only here)
//   K_B: reads  d_out, writes laW = ws   (disjoint)
//   K_C: reads  laW (ws), writes int32 -> d_out   (disjoint read/write)
// Round-9 bug: K_C read and wrote d_out concurrently -> cross-block race.
// ---------------------------------------------------------------------------
extern "C" void kernel_launch(void* const* d_in, const int* in_sizes, int n_in,
                              void* d_out, int out_size, void* d_ws, size_t ws_size,
                              hipStream_t stream) {
    (void)in_sizes; (void)n_in; (void)out_size; (void)ws_size;
    const float* grad = (const float*)d_in[0];
    int* out = (int*)d_out;
    char* ws = (char*)d_ws;

    int* cv = (int*)(ws);                               // 25088 B
    int* ch = (int*)(ws + 25088);                       // 25088 B
    unsigned char* laW = (unsigned char*)(ws + 50176);  // v4 image (ws, 200704 B)
    unsigned char* laD = (unsigned char*)d_out;         // v2 image (inside d_out)

    dp_kernel<<<56, 64, 0, stream>>>(grad, cv, ch);

    dim3 grid(784, 1, 1), blk(256, 1, 1);               // flat; XCD map in-kernel
    labvote12_kernel<<<grid, blk, 0, stream>>>(cv, ch, laD);   // labels+v1+v2 -> d_out
    vote34_kernel<<<grid, blk, 0, stream>>>(laD, laW);         // v3+v4 -> ws
    vote_kernel<<<grid, blk, 0, stream>>>(laW, out);           // v5 -> int32 d_out
}